// Round 1
// baseline (1696.203 us; speedup 1.0000x reference)
//
#include <hip/hip_runtime.h>
#include <hip/hip_bf16.h>
#include <cstdint>
#include <cstddef>

typedef __attribute__((ext_vector_type(8))) short short8;
typedef __attribute__((ext_vector_type(4))) short short4v;
typedef __attribute__((ext_vector_type(4))) float f32x4;

__device__ __forceinline__ float bf2f(unsigned short u) {
  union { unsigned int i; float f; } v; v.i = ((unsigned int)u) << 16; return v.f;
}
__device__ __forceinline__ unsigned short f2bf(float f) {
  union { float f; unsigned int i; } v; v.f = f;
  unsigned int x = v.i;
  return (unsigned short)((x + 0x7fffu + ((x >> 16) & 1u)) >> 16);
}
__device__ __forceinline__ f32x4 mfma16(short8 a, short8 b, f32x4 c) {
  return __builtin_amdgcn_mfma_f32_16x16x32_bf16(a, b, c, 0, 0, 0);
}

// ---------------- fp32 -> bf16 weight conversion ----------------
__global__ __launch_bounds__(256) void k_cvt(const float* __restrict__ src,
                                             unsigned short* __restrict__ dst, int n4) {
  int i = blockIdx.x * 256 + threadIdx.x;
  if (i >= n4) return;
  float4 v = reinterpret_cast<const float4*>(src)[i];
  short4v o;
  o[0] = (short)f2bf(v.x); o[1] = (short)f2bf(v.y);
  o[2] = (short)f2bf(v.z); o[3] = (short)f2bf(v.w);
  reinterpret_cast<short4v*>(dst)[i] = o;
}

// ---------------- fused encoder: patch+mask -> conv1 -> conv2 -> mean pool ----------------
// 1 block = 1 patch (n = b*49 + r*7 + c). Writes x_bf16[n][2048].
__global__ __launch_bounds__(256) void k_encoder(
    const float* __restrict__ images, const int* __restrict__ rnd,
    const unsigned short* __restrict__ w1b, const float* __restrict__ b1,
    const unsigned short* __restrict__ w2b, const float* __restrict__ b2,
    unsigned short* __restrict__ xout)
{
  __shared__ char ldsA[64 * 384];   // im2col [p][192k] bf16, granule-swizzled
  __shared__ char ldsH[64 * 512];   // h1     [p][256ci] bf16, granule-swizzled
  const int n = blockIdx.x;
  const int b = n / 49, rc = n % 49, R = rc / 7, C = rc % 7;
  const int rv = rnd[n];
  const int roff = rv >> 2, coff = rv & 3;
  const int tid = threadIdx.x;

  // stage masked im2col: granule (p, gr): gr = ci*8+ky holds k = gr*8 + kx (kx 0..7)
  for (int g = tid; g < 1536; g += 256) {
    const int p = g / 24, gr = g % 24;
    const int ci = gr >> 3, ky = gr & 7;
    const int oy = p >> 3, ox = p & 7;
    const int y = oy * 8 + ky;
    const float* src = images + (((size_t)(b * 3 + ci) * 256 + (size_t)(R * 32 + y)) * 256
                                 + C * 32 + ox * 8);
    float4 v0 = *reinterpret_cast<const float4*>(src);
    float4 v1 = *reinterpret_cast<const float4*>(src + 4);
    const bool rok = (y >= roff) && (y < roff + 60);
    float vals[8] = { v0.x, v0.y, v0.z, v0.w, v1.x, v1.y, v1.z, v1.w };
    short8 o;
    const int x0 = ox * 8;
#pragma unroll
    for (int q = 0; q < 8; q++) {
      const int xx = x0 + q;
      const bool ok = rok && (xx >= coff) && (xx < coff + 60);
      o[q] = (short)f2bf(ok ? vals[q] : -1.0f);
    }
    const int sw = (gr & ~7) | ((gr & 7) ^ (p & 7));
    *reinterpret_cast<short8*>(ldsA + p * 384 + sw * 16) = o;
  }
  __syncthreads();

  const int w = tid >> 6, lane = tid & 63, lr = lane & 15, lg = lane >> 4;

  // conv1: 256co x 64p, K=192 (wave w owns co [w*64, w*64+64))
  f32x4 acc1[4][4];
  for (int i = 0; i < 4; i++) for (int j = 0; j < 4; j++) acc1[i][j] = (f32x4)0.f;
  for (int kk = 0; kk < 6; kk++) {
    short8 a[4], bb[4];
    const int k = kk * 32 + lg * 8;
#pragma unroll
    for (int cot = 0; cot < 4; cot++) {
      const int co = w * 64 + cot * 16 + lr;
      a[cot] = *reinterpret_cast<const short8*>(w1b + (size_t)co * 192 + k);
    }
    const int gg = kk * 4 + lg;
#pragma unroll
    for (int pt = 0; pt < 4; pt++) {
      const int p = pt * 16 + lr;
      const int sw = (gg & ~7) | ((gg & 7) ^ (p & 7));
      bb[pt] = *reinterpret_cast<const short8*>(ldsA + p * 384 + sw * 16);
    }
#pragma unroll
    for (int cot = 0; cot < 4; cot++)
#pragma unroll
      for (int pt = 0; pt < 4; pt++)
        acc1[cot][pt] = mfma16(a[cot], bb[pt], acc1[cot][pt]);
  }

  // h1 = relu(conv1 + b1) -> LDS [p][ci] bf16 (4 consecutive co packed per 8B write)
#pragma unroll
  for (int cot = 0; cot < 4; cot++) {
    const int cob = w * 64 + cot * 16 + lg * 4;
    float4 bi = *reinterpret_cast<const float4*>(b1 + cob);
    const float bv[4] = { bi.x, bi.y, bi.z, bi.w };
    const int g2 = cob >> 3;
#pragma unroll
    for (int pt = 0; pt < 4; pt++) {
      const int p = pt * 16 + lr;
      short4v o;
#pragma unroll
      for (int r = 0; r < 4; r++)
        o[r] = (short)f2bf(fmaxf(acc1[cot][pt][r] + bv[r], 0.f));
      const int sw = (g2 & ~7) | ((g2 & 7) ^ (p & 7));
      *reinterpret_cast<short4v*>(ldsH + p * 512 + sw * 16 + (cob & 7) * 2) = o;
    }
  }
  __syncthreads();

  // conv2: 2048co x 64p, K=256; relu(+b2); mean over 64 p -> xout[n][co]
  for (int c2 = 0; c2 < 8; c2++) {
    f32x4 acc2[4][4];
    for (int i = 0; i < 4; i++) for (int j = 0; j < 4; j++) acc2[i][j] = (f32x4)0.f;
    for (int kk = 0; kk < 8; kk++) {
      short8 a[4], bb[4];
      const int ci = kk * 32 + lg * 8;
#pragma unroll
      for (int cot = 0; cot < 4; cot++) {
        const int co = c2 * 256 + w * 64 + cot * 16 + lr;
        a[cot] = *reinterpret_cast<const short8*>(w2b + (size_t)co * 256 + ci);
      }
      const int gg = kk * 4 + lg;
#pragma unroll
      for (int pt = 0; pt < 4; pt++) {
        const int p = pt * 16 + lr;
        const int sw = (gg & ~7) | ((gg & 7) ^ (p & 7));
        bb[pt] = *reinterpret_cast<const short8*>(ldsH + p * 512 + sw * 16);
      }
#pragma unroll
      for (int cot = 0; cot < 4; cot++)
#pragma unroll
        for (int pt = 0; pt < 4; pt++)
          acc2[cot][pt] = mfma16(a[cot], bb[pt], acc2[cot][pt]);
    }
#pragma unroll
    for (int cot = 0; cot < 4; cot++) {
      const int cob = c2 * 256 + w * 64 + cot * 16 + lg * 4;
      float4 bi = *reinterpret_cast<const float4*>(b2 + cob);
      const float bv[4] = { bi.x, bi.y, bi.z, bi.w };
      float s[4] = { 0.f, 0.f, 0.f, 0.f };
#pragma unroll
      for (int pt = 0; pt < 4; pt++)
#pragma unroll
        for (int r = 0; r < 4; r++)
          s[r] += fmaxf(acc2[cot][pt][r] + bv[r], 0.f);
#pragma unroll
      for (int r = 0; r < 4; r++)
#pragma unroll
        for (int mk = 1; mk < 16; mk <<= 1)
          s[r] += __shfl_xor(s[r], mk, 64);
      if (lr == 0) {
        short4v o;
#pragma unroll
        for (int r = 0; r < 4; r++) o[r] = (short)f2bf(s[r] * (1.f / 64.f));
        *reinterpret_cast<short4v*>(xout + (size_t)n * 2048 + cob) = o;
      }
    }
  }
}

// ---------------- latents mean over 49 patches -> out[1 + b*2048 + ch] ----------------
__global__ __launch_bounds__(256) void k_out2(const unsigned short* __restrict__ x,
                                              float* __restrict__ out) {
  const int ch = blockIdx.x * 256 + threadIdx.x;
  const int b = blockIdx.y;
  float s = 0.f;
  for (int p = 0; p < 49; p++) s += bf2f(x[(size_t)(b * 49 + p) * 2048 + ch]);
  out[1 + b * 2048 + ch] = s * (1.f / 49.f);
}

// ---------------- generic bf16 MFMA GEMM: out[n][m] = f(in[n][:] . W[m][:] + bias) --------
template<int M_BLK, bool RELU, bool RESID, bool SCALE, bool OBF16>
__global__ __launch_bounds__(256) void k_gemm(
    const unsigned short* __restrict__ in, const unsigned short* __restrict__ W,
    const float* __restrict__ bias, float* __restrict__ outf,
    unsigned short* __restrict__ outb, const unsigned short* __restrict__ res,
    int M, int K, float scale)
{
  constexpr int MF = M_BLK / 64;
  __shared__ char lds[(M_BLK + 64) * 128];
  char* At = lds;
  char* Bt = lds + M_BLK * 128;
  const int tid = threadIdx.x;
  const int m0 = blockIdx.x * M_BLK;
  const int n0 = blockIdx.y * 64;
  const int w = tid >> 6, lane = tid & 63, lr = lane & 15, lg = lane >> 4;
  f32x4 acc[MF][4];
  for (int mf = 0; mf < MF; mf++) for (int nt = 0; nt < 4; nt++) acc[mf][nt] = (f32x4)0.f;
  const int KB = K >> 6;
  const int AG = M_BLK * 8;
  const int TG = AG + 512;
  for (int kb = 0; kb < KB; kb++) {
    __syncthreads();
    for (int g = tid; g < TG; g += 256) {
      int row, slot; const unsigned short* src; char* dst;
      if (g < AG) {
        row = g >> 3; slot = g & 7;
        src = W + (size_t)(m0 + row) * K + kb * 64 + slot * 8;
        dst = At + row * 128 + ((slot ^ (row & 7)) * 16);
      } else {
        const int h = g - AG; row = h >> 3; slot = h & 7;
        src = in + (size_t)(n0 + row) * K + kb * 64 + slot * 8;
        dst = Bt + row * 128 + ((slot ^ (row & 7)) * 16);
      }
      *reinterpret_cast<short8*>(dst) = *reinterpret_cast<const short8*>(src);
    }
    __syncthreads();
#pragma unroll
    for (int kk = 0; kk < 2; kk++) {
      short8 a[MF], bb[4];
      const int gg = kk * 4 + lg;
#pragma unroll
      for (int mf = 0; mf < MF; mf++) {
        const int row = w * (M_BLK / 4) + mf * 16 + lr;
        a[mf] = *reinterpret_cast<const short8*>(At + row * 128 + ((gg ^ (row & 7)) * 16));
      }
#pragma unroll
      for (int nt = 0; nt < 4; nt++) {
        const int row = nt * 16 + lr;
        bb[nt] = *reinterpret_cast<const short8*>(Bt + row * 128 + ((gg ^ (row & 7)) * 16));
      }
#pragma unroll
      for (int mf = 0; mf < MF; mf++)
#pragma unroll
        for (int nt = 0; nt < 4; nt++)
          acc[mf][nt] = mfma16(a[mf], bb[nt], acc[mf][nt]);
    }
  }
#pragma unroll
  for (int mf = 0; mf < MF; mf++) {
    const int mb = m0 + w * (M_BLK / 4) + mf * 16 + lg * 4;
    float bv[4];
    { float4 t4 = *reinterpret_cast<const float4*>(bias + mb);
      bv[0] = t4.x; bv[1] = t4.y; bv[2] = t4.z; bv[3] = t4.w; }
#pragma unroll
    for (int nt = 0; nt < 4; nt++) {
      const size_t nn = (size_t)(n0 + nt * 16 + lr);
      const size_t off = nn * (size_t)M + mb;
      float v[4];
#pragma unroll
      for (int r = 0; r < 4; r++) {
        v[r] = acc[mf][nt][r] + bv[r];
        if (SCALE) v[r] *= scale;
      }
      if (RESID) {
        short4v rv = *reinterpret_cast<const short4v*>(res + off);
#pragma unroll
        for (int r = 0; r < 4; r++) v[r] += bf2f((unsigned short)rv[r]);
      }
#pragma unroll
      for (int r = 0; r < 4; r++) if (RELU) v[r] = fmaxf(v[r], 0.f);
      if (OBF16) {
        short4v o;
#pragma unroll
        for (int r = 0; r < 4; r++) o[r] = (short)f2bf(v[r]);
        *reinterpret_cast<short4v*>(outb + off) = o;
      } else {
        float4 o; o.x = v[0]; o.y = v[1]; o.z = v[2]; o.w = v[3];
        *reinterpret_cast<float4*>(outf + off) = o;
      }
    }
  }
}

// ---------------- PixelCNN 1x3 conv over width (pad 1,1), relu ----------------
__global__ __launch_bounds__(256) void k_conv1x3(
    const float* __restrict__ y1, const float* __restrict__ W,
    const float* __restrict__ bias, float* __restrict__ y2)
{
  __shared__ float t[7 * 256];   // [w][ci]
  const int bh = blockIdx.x;
  const int base = ((bh / 7) * 49 + (bh % 7) * 7) * 256;
  for (int i = threadIdx.x; i < 1792; i += 256) t[i] = y1[base + i];
  __syncthreads();
  const int c = threadIdx.x;
  const float* wp = W + (size_t)c * 768;   // [ci][3]
  float acc[7] = {0,0,0,0,0,0,0};
  for (int ci = 0; ci < 256; ci++) {
    const float w0 = wp[ci*3+0], w1 = wp[ci*3+1], w2 = wp[ci*3+2];
    float v[7];
#pragma unroll
    for (int ww = 0; ww < 7; ww++) v[ww] = t[ww * 256 + ci];
#pragma unroll
    for (int ww = 0; ww < 7; ww++) {
      float s = w1 * v[ww];
      if (ww > 0) s += w0 * v[ww - 1];
      if (ww < 6) s += w2 * v[ww + 1];
      acc[ww] += s;
    }
  }
  const float bc = bias[c];
#pragma unroll
  for (int ww = 0; ww < 7; ww++)
    y2[base + ww * 256 + c] = fmaxf(acc[ww] + bc, 0.f);
}

// ---------------- PixelCNN 2x1 conv over height (pad 1,0), relu, out bf16 ----------------
__global__ __launch_bounds__(256) void k_conv2x1(
    const float* __restrict__ y2, const float* __restrict__ W,
    const float* __restrict__ bias, unsigned short* __restrict__ y3)
{
  __shared__ float t[2 * 7 * 256];   // [s][w][ci], s=0 row h-1, s=1 row h
  const int bh = blockIdx.x;
  const int b = bh / 7, h = bh % 7;
  const int base = (b * 49 + h * 7) * 256;
  for (int i = threadIdx.x; i < 1792; i += 256) {
    t[1792 + i] = y2[base + i];
    t[i] = (h > 0) ? y2[base - 1792 + i] : 0.f;
  }
  __syncthreads();
  const int c = threadIdx.x;
  const float* wp = W + (size_t)c * 512;   // [ci][2]
  float acc[7] = {0,0,0,0,0,0,0};
  for (int ci = 0; ci < 256; ci++) {
    const float w0 = wp[ci*2+0], w1 = wp[ci*2+1];
#pragma unroll
    for (int ww = 0; ww < 7; ww++)
      acc[ww] += w0 * t[ww * 256 + ci] + w1 * t[1792 + ww * 256 + ci];
  }
  const float bc = bias[c];
#pragma unroll
  for (int ww = 0; ww < 7; ww++)
    y3[base + ww * 256 + c] = f2bf(fmaxf(acc[ww] + bc, 0.f));
}

// ---------------- per-row streaming log-softmax loss ----------------
// block = one pred row (b, h, w): -lsm[label] with label row = n + 7*(ip+3)
__global__ __launch_bounds__(256) void k_loss(
    const float* __restrict__ preds, const unsigned short* __restrict__ targ,
    float* __restrict__ lossr, int ip, int lbase)
{
  __shared__ float pl[64];
  __shared__ char tl[256 * 128];
  __shared__ float redM[256];
  __shared__ float redS[256];
  __shared__ float zlab;
  const int tid = threadIdx.x;
  const int cd7 = (4 - ip) * 7;
  const int bi = blockIdx.x;
  const int b = bi / cd7, hw = bi % cd7;
  const int n = b * 49 + hw;
  const int lab = n + 7 * (ip + 3);
  if (tid < 64) pl[tid] = preds[(size_t)n * 64 + tid];
  float m = -1e30f, s = 0.f;
  for (int tile = 0; tile < 13; tile++) {
    __syncthreads();
    for (int g = tid; g < 2048; g += 256) {
      const int row = g >> 3, slot = g & 7;
      const int j = tile * 256 + row;
      short8 v = (short8)(short)0;
      if (j < 3136) v = *reinterpret_cast<const short8*>(targ + (size_t)j * 64 + slot * 8);
      *reinterpret_cast<short8*>(tl + row * 128 + ((slot ^ (row & 7)) * 16)) = v;
    }
    __syncthreads();
    const int j = tile * 256 + tid;
    if (j < 3136) {
      float dot = 0.f;
#pragma unroll
      for (int q8 = 0; q8 < 8; q8++) {
        short8 tv = *reinterpret_cast<const short8*>(tl + tid * 128 + ((q8 ^ (tid & 7)) * 16));
#pragma unroll
        for (int q = 0; q < 8; q++) dot += bf2f((unsigned short)tv[q]) * pl[q8 * 8 + q];
      }
      const float nm = fmaxf(m, dot);
      s = s * __expf(m - nm) + __expf(dot - nm);
      m = nm;
      if (j == lab) zlab = dot;
    }
  }
  redM[tid] = m; redS[tid] = s;
  for (int off = 128; off > 0; off >>= 1) {
    __syncthreads();
    if (tid < off) {
      const float m2 = redM[tid + off], s2 = redS[tid + off];
      const float nm = fmaxf(redM[tid], m2);
      redS[tid] = redS[tid] * __expf(redM[tid] - nm) + s2 * __expf(m2 - nm);
      redM[tid] = nm;
    }
  }
  __syncthreads();
  if (tid == 0) lossr[lbase + bi] = (redM[0] + __logf(redS[0])) - zlab;
}

__global__ __launch_bounds__(256) void k_loss_final(const float* __restrict__ lossr,
                                                    float* __restrict__ out) {
  __shared__ float red[256];
  const int tid = threadIdx.x;
  float s = 0.f;
  for (int i = tid; i < 4032; i += 256) {
    const float wgt = (i < 1792) ? (1.f / 1792.f) : ((i < 3136) ? (1.f / 1344.f) : (1.f / 896.f));
    s += lossr[i] * wgt;
  }
  red[tid] = s;
  for (int off = 128; off > 0; off >>= 1) {
    __syncthreads();
    if (tid < off) red[tid] += red[tid + off];
  }
  if (tid == 0) out[0] = red[0];
}

extern "C" void kernel_launch(void* const* d_in, const int* in_sizes, int n_in,
                              void* d_out, int out_size, void* d_ws, size_t ws_size,
                              hipStream_t stream)
{
  (void)in_sizes; (void)n_in; (void)out_size; (void)ws_size;
  const float* images = (const float*)d_in[0];
  const int*   rnd    = (const int*)d_in[1];
  const float* enc_w1 = (const float*)d_in[2];
  const float* enc_b1 = (const float*)d_in[3];
  const float* enc_w2 = (const float*)d_in[4];
  const float* enc_b2 = (const float*)d_in[5];
  const float* pc_w1  = (const float*)d_in[6];
  const float* pc_b1  = (const float*)d_in[7];
  const float* pc_w2  = (const float*)d_in[8];
  const float* pc_b2  = (const float*)d_in[9];
  const float* pc_w3  = (const float*)d_in[10];
  const float* pc_b3  = (const float*)d_in[11];
  const float* pc_w4  = (const float*)d_in[12];
  const float* pc_b4  = (const float*)d_in[13];
  const float* z2t_w  = (const float*)d_in[14];
  const float* z2t_b  = (const float*)d_in[15];
  const float* c2p_w  = (const float*)d_in[16];
  const float* c2p_b  = (const float*)d_in[17];
  float* out = (float*)d_out;
  char* ws = (char*)d_ws;

  // ws layout (bytes)
  unsigned short* w1b   = (unsigned short*)(ws + 0);          //   98304
  unsigned short* w2b   = (unsigned short*)(ws + 98304);      // +1048576
  unsigned short* pcw1b = (unsigned short*)(ws + 1146880);    // +5242880
  unsigned short* pcw4b = (unsigned short*)(ws + 6389760);    // +5242880
  unsigned short* z2tb  = (unsigned short*)(ws + 11632640);   // + 262144
  unsigned short* c2pb  = (unsigned short*)(ws + 11894784);   // + 786432
  unsigned short* xbuf  = (unsigned short*)(ws + 12681216);   // +12845056
  float*          y1    = (float*)(ws + 25526272);            // +3211264
  float*          y2    = (float*)(ws + 28737536);            // +3211264
  unsigned short* y3    = (unsigned short*)(ws + 31948800);   // +1605632
  unsigned short* targ  = (unsigned short*)(ws + 33554432);   // + 401408
  float*          preds = (float*)(ws + 33955840);            // + 802816
  float*          lossr = (float*)(ws + 34758656);            // +  16128

  // weight conversions
  k_cvt<<<48,   256, 0, stream>>>(enc_w1, w1b,   12288);
  k_cvt<<<512,  256, 0, stream>>>(enc_w2, w2b,   131072);
  k_cvt<<<2560, 256, 0, stream>>>(pc_w1,  pcw1b, 655360);
  k_cvt<<<2560, 256, 0, stream>>>(pc_w4,  pcw4b, 655360);
  k_cvt<<<128,  256, 0, stream>>>(z2t_w,  z2tb,  32768);
  k_cvt<<<384,  256, 0, stream>>>(c2p_w,  c2pb,  98304);

  // encoder -> latents (bf16), latents-mean output, targets (before PixelCNN mutates xbuf)
  k_encoder<<<3136, 256, 0, stream>>>(images, rnd, w1b, enc_b1, w2b, enc_b2, xbuf);
  k_out2<<<dim3(8, 64), 256, 0, stream>>>(xbuf, out);
  k_gemm<64, false, false, false, true><<<dim3(1, 49), 256, 0, stream>>>(
      xbuf, z2tb, z2t_b, nullptr, targ, nullptr, 64, 2048, 1.f);

  // PixelCNN: 5 residual blocks (in-place on xbuf)
  for (int k = 0; k < 5; k++) {
    k_gemm<64, true, false, false, false><<<dim3(4, 49), 256, 0, stream>>>(
        xbuf, pcw1b + (size_t)k * 256 * 2048, pc_b1 + k * 256, y1, nullptr, nullptr,
        256, 2048, 1.f);
    k_conv1x3<<<448, 256, 0, stream>>>(y1, pc_w2 + (size_t)k * 256 * 256 * 3,
                                       pc_b2 + k * 256, y2);
    k_conv2x1<<<448, 256, 0, stream>>>(y2, pc_w3 + (size_t)k * 256 * 256 * 2,
                                       pc_b3 + k * 256, y3);
    k_gemm<128, true, true, false, true><<<dim3(16, 49), 256, 0, stream>>>(
        y3, pcw4b + (size_t)k * 2048 * 256, pc_b4 + k * 2048, nullptr, xbuf, xbuf,
        2048, 256, 1.f);
  }

  // contrastive loss
  const int cd[3] = {4, 3, 2};
  const int lbase[3] = {0, 1792, 3136};
  for (int ip = 0; ip < 3; ip++) {
    k_gemm<64, false, false, true, false><<<dim3(1, 49), 256, 0, stream>>>(
        xbuf, c2pb + (size_t)ip * 64 * 2048, c2p_b + ip * 64, preds, nullptr, nullptr,
        64, 2048, 0.1f);
    k_loss<<<64 * cd[ip] * 7, 256, 0, stream>>>(preds, targ, lossr, ip, lbase[ip]);
  }
  k_loss_final<<<1, 256, 0, stream>>>(lossr, out);
}